// Round 5
// baseline (4266.030 us; speedup 1.0000x reference)
//
#include <hip/hip_runtime.h>

typedef unsigned short u16;
typedef unsigned int   u32;

#define B_    128
#define N_    8192
#define HD_   256
#define X_    768          // 3*HD
#define T_    10
#define SEGS_ 8
#define SEGROWS_ 1024      // N_/SEGS_

// ---- persistent per-call state in device globals ----
__device__ float g_h[B_*HD_];
__device__ float g_c[B_*HD_];
__device__ float g_q[B_*HD_];
__device__ float g_pval[B_*SEGS_*3];
__device__ int   g_pidx[B_*SEGS_*3];
__device__ int   g_isf32;

struct P {
  const void *enc, *h0, *c0, *x0, *Wih, *bih, *Whh, *bhh, *Wq, *bq;
  void* out;
};

#define LDSP(x) ((__attribute__((address_space(3))) void*)(x))
#define GLBP(x) ((const __attribute__((address_space(1))) void*)(x))

__device__ __forceinline__ float bf2f(u16 u){ return __uint_as_float(((u32)u)<<16); }
__device__ __forceinline__ float lo2f(u32 w){ return __uint_as_float(w<<16); }
__device__ __forceinline__ float hi2f(u32 w){ return __uint_as_float(w & 0xffff0000u); }
__device__ __forceinline__ u16 f2bf(float f){
  u32 u = __float_as_uint(f);
  u32 r = u + 0x7fffu + ((u>>16)&1u);   // RNE
  return (u16)(r>>16);
}

template<bool F32>
__device__ __forceinline__ float ld1(const void* p, size_t i){
  if constexpr (F32) return ((const float*)p)[i];
  else               return bf2f(((const u16*)p)[i]);
}

template<bool F32>
__device__ __forceinline__ void st1(void* p, size_t i, float v){
  if constexpr (F32) ((float*)p)[i] = v;
  else               ((u16*)p)[i]   = f2bf(v);
}

template<bool F32>
__device__ __forceinline__ void ld8(const void* p, size_t i, float* o){
  if constexpr (F32){
    const float4* q = (const float4*)((const float*)p + i);
    float4 a = q[0], b = q[1];
    o[0]=a.x; o[1]=a.y; o[2]=a.z; o[3]=a.w;
    o[4]=b.x; o[5]=b.y; o[6]=b.z; o[7]=b.w;
  } else {
    uint4 u = *(const uint4*)((const u16*)p + i);
    o[0]=lo2f(u.x); o[1]=hi2f(u.x); o[2]=lo2f(u.y); o[3]=hi2f(u.y);
    o[4]=lo2f(u.z); o[5]=hi2f(u.z); o[6]=lo2f(u.w); o[7]=hi2f(u.w);
  }
}

// top-3 insert, jax.lax.top_k tie-break (equal value -> lower index first)
__device__ __forceinline__ void t3ins(float v,int i,
    float&v0,int&i0,float&v1,int&i1,float&v2,int&i2){
  if (v>v0 || (v==v0 && i<i0)) { v2=v1;i2=i1; v1=v0;i1=i0; v0=v;i0=i; }
  else if (v>v1 || (v==v1 && i<i1)) { v2=v1;i2=i1; v1=v;i1=i; }
  else if (v>v2 || (v==v2 && i<i2)) { v2=v;i2=i; }
}

// ---- dtype probe ----
__global__ void k_probe(const void* enc){
  const int lane = threadIdx.x;           // 64 threads
  const u16 u = ((const u16*)enc)[lane*2];
  const float a = fabsf(bf2f(u));
  const bool inr = (a >= 0.0009765625f) && (a <= 1024.0f);
  unsigned long long m = __ballot(inr ? 1 : 0);
  if (lane==0) g_isf32 = (__popcll(m) < 32) ? 1 : 0;
}

// ---- K1: merge prev partials -> idx output + gather x, LSTM, query ----
template<bool F32>
__device__ void lstm_b(const P& p, int t, int b)
{
  const int d = threadIdx.x;
  __shared__ float xs[X_];
  __shared__ float hs[HD_];
  __shared__ float hn[HD_];
  __shared__ int   idx3[3];

  float cd;
  if (t == 0){
    for (int i=d;i<X_;i+=256) xs[i] = ld1<F32>(p.x0, (size_t)b*X_+i);
    hs[d] = ld1<F32>(p.h0, (size_t)b*HD_+d);
    cd    = ld1<F32>(p.c0, (size_t)b*HD_+d);
  } else {
    if (d==0){
      float v0=-3.4e38f,v1=-3.4e38f,v2=-3.4e38f; int i0=-1,i1=-1,i2=-1;
      const float* pv = g_pval + b*SEGS_*3;
      const int*   pi = g_pidx + b*SEGS_*3;
      for (int s=0;s<SEGS_*3;s++) t3ins(pv[s],pi[s],v0,i0,v1,i1,v2,i2);
      idx3[0]=i0; idx3[1]=i1; idx3[2]=i2;
      const size_t ib = (size_t)T_*B_*N_ + (size_t)(t-1)*B_*3 + (size_t)b*3;
      st1<F32>(p.out, ib+0, (float)i0);
      st1<F32>(p.out, ib+1, (float)i1);
      st1<F32>(p.out, ib+2, (float)i2);
    }
    __syncthreads();
    #pragma unroll
    for (int j=0;j<3;j++){
      int jj = idx3[j]; jj = jj<0 ? 0 : (jj>N_-1 ? N_-1 : jj);   // crash guard
      xs[j*HD_+d] = ld1<F32>(p.enc, ((size_t)b*N_ + jj)*HD_ + d);
    }
    hs[d] = g_h[b*HD_+d];
    cd    = g_c[b*HD_+d];
  }
  __syncthreads();

  float g4[4];
  #pragma unroll
  for (int gi=0;gi<4;gi++){
    const int row = gi*HD_ + d;
    float acc = ld1<F32>(p.bih,row) + ld1<F32>(p.bhh,row);
    #pragma unroll 4
    for (int kk=0;kk<X_/8;kk++){
      float w[8]; ld8<F32>(p.Wih, (size_t)row*X_ + kk*8, w);
      #pragma unroll
      for (int j=0;j<8;j++) acc = fmaf(xs[kk*8+j], w[j], acc);
    }
    #pragma unroll 4
    for (int kk=0;kk<HD_/8;kk++){
      float w[8]; ld8<F32>(p.Whh, (size_t)row*HD_ + kk*8, w);
      #pragma unroll
      for (int j=0;j<8;j++) acc = fmaf(hs[kk*8+j], w[j], acc);
    }
    g4[gi]=acc;
  }
  const float sig_i = 1.f/(1.f+expf(-g4[0]));
  const float sig_f = 1.f/(1.f+expf(-g4[1]));
  const float tan_g = tanhf(g4[2]);
  const float sig_o = 1.f/(1.f+expf(-g4[3]));
  const float cn = sig_f*cd + sig_i*tan_g;
  const float hv = sig_o*tanhf(cn);
  g_c[b*HD_+d]=cn; g_h[b*HD_+d]=hv; hn[d]=hv;
  __syncthreads();

  float acc = ld1<F32>(p.bq,d);
  #pragma unroll 4
  for (int kk=0;kk<HD_/8;kk++){
    float w[8]; ld8<F32>(p.Wq, (size_t)d*HD_ + kk*8, w);
    #pragma unroll
    for (int j=0;j<8;j++) acc = fmaf(hn[kk*8+j], w[j], acc);
  }
  g_q[b*HD_+d]=acc;
}

__global__ __launch_bounds__(256) void k_lstm(P p, int t)
{
  if (g_isf32) lstm_b<true >(p, t, blockIdx.x);
  else         lstm_b<false>(p, t, blockIdx.x);
}

// ---- K2: logits. 1-wave blocks; LDS-staged tiles via global_load_lds with
// source-side XOR swizzle (dest linear); each lane dots one full row from LDS.
// No shfl / branches / stores in the hot loop except one coalesced 2B store
// and one t3ins per completed row.
template<bool F32>
__device__ void logits_b(const P& p, int t, int b, int seg)
{
  __shared__ uint4 tile[2048];   // 32 KB
  __shared__ float qs[HD_];      // 1 KB
  const int l = threadIdx.x;     // 0..63

  for (int i=l;i<HD_;i+=64) qs[i] = g_q[b*HD_+i];
  __syncthreads();

  float v0=-3.4e38f,v1=-3.4e38f,v2=-3.4e38f; int i0=-1,i1=-1,i2=-1;

  const size_t segelem = ((size_t)b*N_ + (size_t)seg*SEGROWS_)*HD_;
  const size_t obase   = (size_t)t*B_*N_ + (size_t)b*N_ + (size_t)seg*SEGROWS_;

  if constexpr (!F32){
    const u16* encb = (const u16*)p.enc + segelem;
    for (int tl=0; tl<16; ++tl){           // 16 tiles x 64 rows x 512 B
      asm volatile("s_waitcnt lgkmcnt(0)" ::: "memory");  // tile reads done
      #pragma unroll
      for (int i=0;i<32;i++){
        const int row = 2*i + (l>>5);      // slot i*64+l -> (row, kp=l&31)
        const int ks  = (l & 31) ^ (row & 7);
        const u16* src = encb + ((size_t)(tl*64 + row))*HD_ + ks*8;
        __builtin_amdgcn_global_load_lds(GLBP(src), LDSP(&tile[i*64]), 16, 0, 0);
      }
      asm volatile("s_waitcnt vmcnt(0)" ::: "memory");
      float acc = 0.f;
      #pragma unroll 8
      for (int k=0;k<32;k++){
        uint4 u = tile[(l<<5) + (k ^ (l & 7))];
        const float* qk = &qs[k*8];
        acc = fmaf(lo2f(u.x), qk[0], acc);
        acc = fmaf(hi2f(u.x), qk[1], acc);
        acc = fmaf(lo2f(u.y), qk[2], acc);
        acc = fmaf(hi2f(u.y), qk[3], acc);
        acc = fmaf(lo2f(u.z), qk[4], acc);
        acc = fmaf(hi2f(u.z), qk[5], acc);
        acc = fmaf(lo2f(u.w), qk[6], acc);
        acc = fmaf(hi2f(u.w), qk[7], acc);
      }
      t3ins(acc, seg*SEGROWS_ + tl*64 + l, v0,i0,v1,i1,v2,i2);
      ((u16*)p.out)[obase + tl*64 + l] = f2bf(acc);
    }
  } else {
    const float* encb = (const float*)p.enc + segelem;
    for (int tl=0; tl<32; ++tl){           // 32 tiles x 32 rows x 1 KB
      asm volatile("s_waitcnt lgkmcnt(0)" ::: "memory");
      #pragma unroll
      for (int i=0;i<32;i++){
        const int row = i;                 // slot i*64+l -> (row=i, kp=l)
        const int ks  = l ^ (row & 7);
        const float* src = encb + ((size_t)(tl*32 + row))*HD_ + ks*4;
        __builtin_amdgcn_global_load_lds(GLBP(src), LDSP(&tile[i*64]), 16, 0, 0);
      }
      asm volatile("s_waitcnt vmcnt(0)" ::: "memory");
      const int r  = l & 31;
      const int kh = (l>>5)*32;
      float acc = 0.f;
      #pragma unroll 8
      for (int k=0;k<32;k++){
        const int kk = kh + k;
        uint4 u = tile[(r<<6) + (kk ^ (r & 7))];
        const float* qk = &qs[kk*4];
        acc = fmaf(__uint_as_float(u.x), qk[0], acc);
        acc = fmaf(__uint_as_float(u.y), qk[1], acc);
        acc = fmaf(__uint_as_float(u.z), qk[2], acc);
        acc = fmaf(__uint_as_float(u.w), qk[3], acc);
      }
      acc += __shfl_xor(acc, 32, 64);      // fold column halves (once per tile)
      if (l < 32){
        t3ins(acc, seg*SEGROWS_ + tl*32 + r, v0,i0,v1,i1,v2,i2);
        ((float*)p.out)[obase + tl*32 + r] = acc;
      }
    }
  }

  // wave butterfly top-3 merge (outside hot loop)
  #pragma unroll
  for (int d=1; d<64; d<<=1){
    float w0=__shfl_xor(v0,d,64), w1=__shfl_xor(v1,d,64), w2=__shfl_xor(v2,d,64);
    int   j0=__shfl_xor(i0,d,64), j1=__shfl_xor(i1,d,64), j2=__shfl_xor(i2,d,64);
    t3ins(w0,j0, v0,i0,v1,i1,v2,i2);
    t3ins(w1,j1, v0,i0,v1,i1,v2,i2);
    t3ins(w2,j2, v0,i0,v1,i1,v2,i2);
  }
  if (l==0){
    float* pv = g_pval + (b*SEGS_+seg)*3;
    int*   pi = g_pidx + (b*SEGS_+seg)*3;
    pv[0]=v0; pv[1]=v1; pv[2]=v2;
    pi[0]=i0; pi[1]=i1; pi[2]=i2;
  }
}

__global__ __launch_bounds__(64) void k_logits(P p, int t)
{
  const int b   = blockIdx.x >> 3;
  const int seg = blockIdx.x & 7;
  if (g_isf32) logits_b<true >(p, t, b, seg);
  else         logits_b<false>(p, t, b, seg);
}

// ---- K3: final merge for the last step's indices ----
template<bool F32>
__device__ void final_b(const P& p, int b)
{
  if (threadIdx.x==0){
    float v0=-3.4e38f,v1=-3.4e38f,v2=-3.4e38f; int i0=-1,i1=-1,i2=-1;
    const float* pv = g_pval + b*SEGS_*3;
    const int*   pi = g_pidx + b*SEGS_*3;
    for (int s=0;s<SEGS_*3;s++) t3ins(pv[s],pi[s],v0,i0,v1,i1,v2,i2);
    const size_t ib = (size_t)T_*B_*N_ + (size_t)(T_-1)*B_*3 + (size_t)b*3;
    st1<F32>(p.out, ib+0, (float)i0);
    st1<F32>(p.out, ib+1, (float)i1);
    st1<F32>(p.out, ib+2, (float)i2);
  }
}

__global__ void k_final(P p)
{
  if (g_isf32) final_b<true >(p, blockIdx.x);
  else         final_b<false>(p, blockIdx.x);
}

extern "C" void kernel_launch(void* const* d_in, const int* in_sizes, int n_in,
                              void* d_out, int out_size, void* d_ws, size_t ws_size,
                              hipStream_t stream)
{
  (void)in_sizes; (void)n_in; (void)out_size; (void)d_ws; (void)ws_size;
  P p;
  p.enc = d_in[0];
  p.h0  = d_in[1];
  p.c0  = d_in[2];
  // d_in[3] end_node_embed: unused in prediction mode
  p.x0  = d_in[4];
  p.Wih = d_in[5];
  p.bih = d_in[6];
  p.Whh = d_in[7];
  p.bhh = d_in[8];
  p.Wq  = d_in[9];
  p.bq  = d_in[10];
  // d_in[11] max_steps == 10 (fixed by setup_inputs)
  p.out = d_out;

  k_probe<<<dim3(1),dim3(64),0,stream>>>(p.enc);

  for (int t=0;t<T_;t++){
    k_lstm  <<<dim3(B_),        dim3(256),0,stream>>>(p, t);
    k_logits<<<dim3(B_*SEGS_),  dim3(64), 0,stream>>>(p, t);
  }
  k_final<<<dim3(B_),dim3(64),0,stream>>>(p);
}